// Round 9
// baseline (56.670 us; speedup 1.0000x reference)
//
#include <hip/hip_runtime.h>
#include <stdint.h>

// KeepTopN: inputs (32, 56, 56, 256) f32, n = 48 (k-th largest per row).
// v9: block-specialized single streaming kernel:
//   - scan blocks: BRANCH-FREE load+max+bitmask loop (copy-like, pipelines),
//     rare tail re-reads flagged float4s from L2 and records u16 positions.
//   - fill blocks: grid-stride nontemporal zero-fill of out.
// Then k_sel: parallel exact radix-select + scatter survivors; inline
// full-row fallback (never taken on N(0,1) data) keeps correctness
// unconditional.
#define ROWS 32
#define ROW_LEN 802816         // 56*56*256
#define ROW_LEN4 200704        // ROW_LEN / 4
#define THREADS 256

// scan geometry
#define SBPR 49                // scan blocks per row
#define TILE_F4 4096           // float4 per scan tile
#define TILE_EL 16384          // elements per tile (u16-indexable)
#define F4_PT 16               // float4 per thread (16-bit mask)
#define SCAN_BLOCKS (ROWS * SBPR)   // 1568
#define TG 3.0f                // speculative threshold; E[cand/tile] ~= 22
#define BCAP 96                // per-tile candidate cap (15 sigma margin)
#define CAP_ROW (SBPR * BCAP)  // 4704
#define SLOTS_PT 19            // ceil(4704/256)

// fill geometry
#define FILL_BLOCKS 1024
#define OUT_F4 (ROWS * ROW_LEN4)    // 6422528

// ws layout (bytes), ~307 KB:
//   pos16 : u16[ROWS][SBPR][BCAP] @ 0       (301056)  elem offset within tile
//   bcnt  : i32[SCAN_BLOCKS]      @ 301056  (6272)    always fully rewritten
//   thr   : f32[ROWS]             @ 307328  (128)
#define OFF_BCNT 301056
#define OFF_THR  307328

typedef float f32x4 __attribute__((ext_vector_type(4)));

// Monotone order-preserving f32 -> u32 key (larger float -> larger key).
__device__ __forceinline__ uint32_t fkey(float x) {
    uint32_t u = __float_as_uint(x);
    return (u & 0x80000000u) ? ~u : (u | 0x80000000u);
}
__device__ __forceinline__ float fkey_inv(uint32_t k) {
    uint32_t u = (k & 0x80000000u) ? (k & 0x7FFFFFFFu) : ~k;
    return __uint_as_float(u);
}

// Pass 1: scan blocks stream input branch-free; fill blocks zero the output.
__global__ __launch_bounds__(THREADS) void k_main(const float* __restrict__ in,
                                                  float* __restrict__ out,
                                                  uint16_t* __restrict__ pos16,
                                                  int* __restrict__ bcnt) {
    const int bid = blockIdx.x;
    if (bid < SCAN_BLOCKS) {
        __shared__ uint32_t lp[BCAP];
        __shared__ int lcnt;
        if (threadIdx.x == 0) lcnt = 0;
        __syncthreads();
        const int row = bid / SBPR, sub = bid % SBPR;
        const size_t tile_f4 = (size_t)row * ROW_LEN4 + (size_t)sub * TILE_F4;
        const float4* p = (const float4*)in + tile_f4 + threadIdx.x;

        // Hot loop: load + max + mask accumulate. No branch, no LDS, no store.
        uint32_t cmask = 0;
#pragma unroll
        for (int it = 0; it < F4_PT; ++it) {
            const float4 d = p[it * THREADS];
            const float mx = fmaxf(fmaxf(d.x, d.y), fmaxf(d.z, d.w));
            cmask |= (mx > TG) ? (1u << it) : 0u;
        }
        // Rare tail: re-read flagged float4s (L2-hit) and record positions.
        while (cmask) {
            const int it = __builtin_ctz(cmask);
            cmask &= cmask - 1;
            const float4 d = p[it * THREADS];
            const uint32_t e = (uint32_t)(it * THREADS + threadIdx.x) * 4u;
            if (d.x > TG) { int j = atomicAdd(&lcnt, 1); if (j < BCAP) lp[j] = e + 0u; }
            if (d.y > TG) { int j = atomicAdd(&lcnt, 1); if (j < BCAP) lp[j] = e + 1u; }
            if (d.z > TG) { int j = atomicAdd(&lcnt, 1); if (j < BCAP) lp[j] = e + 2u; }
            if (d.w > TG) { int j = atomicAdd(&lcnt, 1); if (j < BCAP) lp[j] = e + 3u; }
        }
        __syncthreads();
        const int c = lcnt;
        if (threadIdx.x == 0) bcnt[bid] = c;   // raw; overflow detected in k_sel
        const int cc = c < BCAP ? c : BCAP;
        for (int i = threadIdx.x; i < cc; i += THREADS)
            pos16[(size_t)bid * BCAP + i] = (uint16_t)lp[i];
    } else {
        // Zero-fill out: grid-stride nontemporal stores (write-once stream).
        const int fb = bid - SCAN_BLOCKS;
        const f32x4 z = {0.f, 0.f, 0.f, 0.f};
        f32x4* q = (f32x4*)out;
        for (size_t i = (size_t)fb * THREADS + threadIdx.x; i < (size_t)OUT_F4;
             i += (size_t)FILL_BLOCKS * THREADS)
            __builtin_nontemporal_store(z, q + i);
    }
}

// Parallel digit pick: histogram h[256] -> inclusive suffix scan across the
// 256 threads (Hillis-Steele, 8 steps) -> digit d with S[d] >= r > S[d+1].
__device__ __forceinline__ void pick_digit(uint32_t* h, int t, int r,
                                           int* sh_sel, int* sh_rank) {
#pragma unroll
    for (int off = 1; off < 256; off <<= 1) {
        uint32_t v = h[t] + ((t + off < 256) ? h[t + off] : 0u);
        __syncthreads();
        h[t] = v;
        __syncthreads();
    }
    const uint32_t Sd = h[t];
    const uint32_t Sd1 = (t < 255) ? h[t + 1] : 0u;
    if ((int)Sd >= r && (int)Sd1 < r) { *sh_sel = t; *sh_rank = r - (int)Sd1; }
    __syncthreads();
}

// Pass 2: per row: gather candidate keys (input is L2/L3-resident), exact
// 4x8-bit radix select of the n-th largest, scatter survivors into the
// zeroed output. Fallback (!ok): full-row radix + full-row masked write.
__global__ __launch_bounds__(THREADS) void k_sel(const float* __restrict__ in,
                                                 const int* __restrict__ n_ptr,
                                                 const int* __restrict__ bcnt,
                                                 const uint16_t* __restrict__ pos16,
                                                 float* __restrict__ out,
                                                 float* __restrict__ thr) {
    __shared__ int lb[SBPR];
    __shared__ uint32_t h[256];
    __shared__ int sh_sel, sh_rank, sh_m, sh_bad;
    const int row = blockIdx.x;
    const int t = threadIdx.x;
    const int n = *n_ptr;
    const float* rin = in + (size_t)row * ROW_LEN;
    float* rout = out + (size_t)row * ROW_LEN;

    if (t == 0) { sh_m = 0; sh_bad = 0; }
    __syncthreads();
    {
        int lsum = 0, lbad = 0;
        for (int b = t; b < SBPR; b += THREADS) {
            const int c = bcnt[row * SBPR + b];
            lbad |= (c > BCAP);
            const int cc = c < BCAP ? c : BCAP;
            lb[b] = cc;
            lsum += cc;
        }
        if (lsum) atomicAdd(&sh_m, lsum);
        if (lbad) atomicOr(&sh_bad, 1);
    }
    __syncthreads();
    const int m = sh_m;
    const bool ok = (!sh_bad) && (m >= n) && (n >= 1);

    if (ok) {
        // Coalesced slot load + gathered key fetch (cache-resident input).
        uint32_t key[SLOTS_PT];
        uint32_t ps[SLOTS_PT];
        bool val[SLOTS_PT];
#pragma unroll
        for (int j = 0; j < SLOTS_PT; ++j) {
            const int slot = j * THREADS + t;
            uint32_t k = 0, pp = 0; bool v = false;
            if (slot < CAP_ROW) {
                const int b = slot / BCAP;
                v = (slot - b * BCAP) < lb[b];
                if (v) {
                    pp = (uint32_t)b * TILE_EL + pos16[(size_t)row * CAP_ROW + slot];
                    k = fkey(rin[pp]);
                }
            }
            key[j] = k; ps[j] = pp; val[j] = v;
        }
        uint32_t prefix = 0, msk = 0;
        int r = n;
        for (int rd = 0; rd < 4; ++rd) {
            const int shn = 24 - rd * 8;
            h[t] = 0;
            __syncthreads();
#pragma unroll
            for (int j = 0; j < SLOTS_PT; ++j)
                if (val[j] && (key[j] & msk) == prefix)
                    atomicAdd(&h[(key[j] >> shn) & 255u], 1u);
            __syncthreads();
            pick_digit(h, t, r, &sh_sel, &sh_rank);
            prefix |= ((uint32_t)sh_sel) << shn;
            msk |= 255u << shn;
            r = sh_rank;
            __syncthreads();
        }
        // Scatter survivors (key >= prefix <=> value >= threshold).
#pragma unroll
        for (int j = 0; j < SLOTS_PT; ++j)
            if (val[j] && key[j] >= prefix)
                rout[ps[j]] = fkey_inv(key[j]);
        if (t == 0) thr[row] = fkey_inv(prefix);
    } else {
        // Exact fallback: full-row radix select + full-row masked write.
        uint32_t prefix = 0, msk = 0;
        int r = (n < 1) ? 1 : n;
        const float4* p = (const float4*)rin;
        for (int rd = 0; rd < 4; ++rd) {
            const int shn = 24 - rd * 8;
            h[t] = 0;
            __syncthreads();
            for (int i = t; i < ROW_LEN4; i += THREADS) {
                const float4 d = p[i];
                uint32_t k;
                k = fkey(d.x); if ((k & msk) == prefix) atomicAdd(&h[(k >> shn) & 255u], 1u);
                k = fkey(d.y); if ((k & msk) == prefix) atomicAdd(&h[(k >> shn) & 255u], 1u);
                k = fkey(d.z); if ((k & msk) == prefix) atomicAdd(&h[(k >> shn) & 255u], 1u);
                k = fkey(d.w); if ((k & msk) == prefix) atomicAdd(&h[(k >> shn) & 255u], 1u);
            }
            __syncthreads();
            pick_digit(h, t, r, &sh_sel, &sh_rank);
            prefix |= ((uint32_t)sh_sel) << shn;
            msk |= 255u << shn;
            r = sh_rank;
            __syncthreads();
        }
        const float tf = fkey_inv(prefix);
        float4* q = (float4*)rout;
        for (int i = t; i < ROW_LEN4; i += THREADS) {
            float4 d = p[i];
            d.x = (d.x >= tf) ? d.x : 0.0f;
            d.y = (d.y >= tf) ? d.y : 0.0f;
            d.z = (d.z >= tf) ? d.z : 0.0f;
            d.w = (d.w >= tf) ? d.w : 0.0f;
            q[i] = d;
        }
        if (t == 0) thr[row] = tf;
    }
}

extern "C" void kernel_launch(void* const* d_in, const int* in_sizes, int n_in,
                              void* d_out, int out_size, void* d_ws, size_t ws_size,
                              hipStream_t stream) {
    const float* in = (const float*)d_in[0];
    const int* n_ptr = (const int*)d_in[1];
    float* out = (float*)d_out;
    char* ws = (char*)d_ws;

    uint16_t* pos16 = (uint16_t*)ws;
    int* bcnt = (int*)(ws + OFF_BCNT);
    float* thr = (float*)(ws + OFF_THR);

    k_main<<<SCAN_BLOCKS + FILL_BLOCKS, THREADS, 0, stream>>>(in, out, pos16, bcnt);
    k_sel<<<ROWS, THREADS, 0, stream>>>(in, n_ptr, bcnt, pos16, out, thr);
}